// Round 7
// baseline (196.248 us; speedup 1.0000x reference)
//
#include <hip/hip_runtime.h>

// LiftSplatShoot dims
#define B_   8
#define N_   6
#define D_   41
#define FH_  8
#define FW_  22
#define C_   64
#define NPRIME (B_*N_*D_*FH_*FW_)   // 346368 = 1353 * 256 exactly
#define NBLK_PTS 1353
#define PTS_PER_CAM (D_*FH_*FW_)    // 7216
#define NX0  200
#define NX1  200
#define G1H  2                      // g1 halves of 100
#define NB2  (B_ * NX0 * G1H)       // 3200 buckets (b, g0, g1/100)
#define OUTSZ (B_*C_*NX0*NX1)       // 20,480,000 floats
#define RROWS 4                     // g0 rows per render group
#define NGRP  50                    // 200/4 exactly -- no ragged tail
#define KINT  25                    // interleave classes: block k does g=k, k+25
#define NCH   4                     // channels per render block (float4 x_feats load)

// ---------------- numpy-faithful fp32 3x3 inverse (LAPACK sgetrf+sgetri) ----
__device__ void lapack_inv3_f32(const float Ain[9], float Aout[9]) {
    #pragma clang fp contract(off)
    float a[9]; // column-major
    for (int r = 0; r < 3; ++r)
        for (int c = 0; c < 3; ++c)
            a[c*3 + r] = Ain[r*3 + c];
    int ipiv[3];
    for (int j = 0; j < 3; ++j) {
        int p = j;
        float amax = fabsf(a[j*3 + j]);
        for (int i = j + 1; i < 3; ++i) {
            float v = fabsf(a[j*3 + i]);
            if (v > amax) { amax = v; p = i; }
        }
        ipiv[j] = p;
        if (p != j)
            for (int c = 0; c < 3; ++c) { float t = a[c*3+j]; a[c*3+j] = a[c*3+p]; a[c*3+p] = t; }
        float d = 1.0f / a[j*3 + j];
        for (int i = j + 1; i < 3; ++i) a[j*3 + i] = a[j*3 + i] * d;
        for (int jj = j + 1; jj < 3; ++jj) {
            float temp = -a[jj*3 + j];
            for (int ii = j + 1; ii < 3; ++ii)
                a[jj*3 + ii] = a[jj*3 + ii] + a[j*3 + ii] * temp;
        }
    }
    for (int j = 0; j < 3; ++j) {
        float ajj_inv = 1.0f / a[j*3 + j];
        a[j*3 + j] = ajj_inv;
        float AJJ = -ajj_inv;
        for (int jj = 0; jj < j; ++jj) {
            float temp = a[j*3 + jj];
            for (int i = 0; i < jj; ++i)
                a[j*3 + i] = a[j*3 + i] + temp * a[jj*3 + i];
            a[j*3 + jj] = a[j*3 + jj] * a[jj*3 + jj];
        }
        for (int i = 0; i < j; ++i) a[j*3 + i] = a[j*3 + i] * AJJ;
    }
    float work[3];
    for (int j = 2; j >= 0; --j) {
        for (int i = j + 1; i < 3; ++i) { work[i] = a[j*3 + i]; a[j*3 + i] = 0.0f; }
        for (int jj = j + 1; jj < 3; ++jj) {
            float temp = -work[jj];
            for (int i = 0; i < 3; ++i)
                a[j*3 + i] = a[j*3 + i] + temp * a[jj*3 + i];
        }
    }
    for (int j = 2; j >= 0; --j) {
        int p = ipiv[j];
        if (p != j)
            for (int i = 0; i < 3; ++i) { float t = a[j*3+i]; a[j*3+i] = a[p*3+i]; a[p*3+i] = t; }
    }
    for (int r = 0; r < 3; ++r)
        for (int c = 0; c < 3; ++c)
            Aout[r*3 + c] = a[c*3 + r];
}

// prep (threads 0..47) + zero bucket counters.
__global__ void prep_kernel(const float* __restrict__ rots,
                            const float* __restrict__ trans,
                            const float* __restrict__ intrins,
                            const float* __restrict__ post_rots,
                            const float* __restrict__ post_trans,
                            float* __restrict__ mats,
                            int* __restrict__ counts) {
    #pragma clang fp contract(off)
    int t = threadIdx.x;
    for (int i = t; i < NB2; i += 256) counts[i] = 0;
    if (t >= B_ * N_) return;
    float pr[9], ipr[9], K[9], iK[9];
    for (int i = 0; i < 9; ++i) { pr[i] = post_rots[t*9 + i]; K[i] = intrins[t*9 + i]; }
    lapack_inv3_f32(pr, ipr);
    lapack_inv3_f32(K, iK);
    float* m = mats + t * 24;
    for (int i = 0; i < 9; ++i) m[i] = ipr[i];
    for (int i = 0; i < 3; ++i)
        for (int k = 0; k < 3; ++k) {
            float s = rots[t*9 + i*3 + 0] * iK[0*3 + k];
            s = s + rots[t*9 + i*3 + 1] * iK[1*3 + k];
            s = s + rots[t*9 + i*3 + 2] * iK[2*3 + k];
            m[9 + i*3 + k] = s;
        }
    for (int i = 0; i < 3; ++i) {
        m[18 + i] = post_trans[t*3 + i];
        m[21 + i] = trans[t*3 + i];
    }
}

// One thread per point (grid exact): fp32 numpy-faithful geometry ->
// pcode=(bk<<7)|r; block-local LDS histogram -> flush.
__global__ void __launch_bounds__(256) geom_kernel(
        const float* __restrict__ mats,
        unsigned int* __restrict__ pcode,
        int* __restrict__ counts) {
    #pragma clang fp contract(off)
    __shared__ unsigned int hist[NB2];   // 12.8 KB
    int t = threadIdx.x;
    int p = blockIdx.x * 256 + t;
    for (int i = t; i < NB2; i += 256) hist[i] = 0u;
    __syncthreads();

    int w  = p % FW_;
    int h  = (p / FW_) % FH_;
    int d  = (p / (FW_ * FH_)) % D_;
    int bn = p / PTS_PER_CAM;
    int b  = bn / N_;

    const float* m = mats + bn * 24;

    float xs = (w == FW_ - 1) ? 351.0f : (float)((double)w * (351.0 / 21.0));
    float ys = (h == FH_ - 1) ? 127.0f : (float)((double)h * (127.0 / 7.0));
    float ds = 4.0f + (float)d;

    float px = xs - m[18], py = ys - m[19], pz = ds - m[20];
    float qx = m[0]*px;  qx = qx + m[1]*py;  qx = qx + m[2]*pz;
    float qy = m[3]*px;  qy = qy + m[4]*py;  qy = qy + m[5]*pz;
    float qz = m[6]*px;  qz = qz + m[7]*py;  qz = qz + m[8]*pz;

    float ux = qx * qz, uy = qy * qz, uz = qz;

    float gx = m[9]*ux;   gx = gx + m[10]*uy;  gx = gx + m[11]*uz;  gx = gx + m[21];
    float gy = m[12]*ux;  gy = gy + m[13]*uy;  gy = gy + m[14]*uz;  gy = gy + m[22];
    float gz = m[15]*ux;  gz = gz + m[16]*uy;  gz = gz + m[17]*uz;  gz = gz + m[23];

    float cx = (gx - (-50.0f)) / 0.5f;
    float cy = (gy - (-50.0f)) / 0.5f;
    float cz = (gz - (-10.0f)) / 20.0f;
    int g0 = (int)cx;
    int g1 = (int)cy;
    int g2 = (int)cz;

    bool kept = (g0 >= 0) && (g0 < NX0) && (g1 >= 0) && (g1 < NX1) && (g2 == 0);
    if (kept) {
        int g1h = g1 / 100;
        int r   = g1 - g1h * 100;
        int bk  = (b * NX0 + g0) * G1H + g1h;
        pcode[p] = ((unsigned int)bk << 7) | (unsigned int)r;
        atomicAdd(&hist[bk], 1u);
    } else {
        pcode[p] = 0xFFFFFFFFu;
    }
    __syncthreads();
    for (int i = t; i < NB2; i += 256) {
        unsigned int hv = hist[i];
        if (hv) atomicAdd(&counts[i], (int)hv);
    }
}

// Single-block (128 threads): pure exclusive scan over 3200 counts ->
// offsets (+total at [NB2]) and cursor.
__global__ void scan_kernel(const int* __restrict__ counts,
                            int* __restrict__ offsets,
                            int* __restrict__ cursor) {
    __shared__ int ts[128];
    int t = threadIdx.x;
    const int PER = NB2 / 128; // 25
    int base = t * PER;
    int mysum = 0;
    for (int j = 0; j < PER; ++j) mysum += counts[base + j];
    ts[t] = mysum;
    __syncthreads();
    for (int off = 1; off < 128; off <<= 1) {
        int v = (t >= off) ? ts[t - off] : 0;
        __syncthreads();
        ts[t] += v;
        __syncthreads();
    }
    int run = (t > 0) ? ts[t - 1] : 0;
    for (int j = 0; j < PER; ++j) {
        offsets[base + j] = run;
        cursor[base + j]  = run;
        run += counts[base + j];
    }
    if (t == 127) offsets[NB2] = run;
}

// Compact kept points (block-aggregated reservation). Entry encodes
// (g0&15)<<27 | g1<<19 | p. Render groups have bases that are multiples
// of 4, so row-local = (g0&15)&3.
__global__ void __launch_bounds__(256) place_kernel(
        const unsigned int* __restrict__ pcode,
        int* __restrict__ cursor,
        unsigned int* __restrict__ entries) {
    __shared__ int cnt[NB2];   // 12.8 KB (counts, then global bases)
    int t = threadIdx.x;
    int p = blockIdx.x * 256 + t;
    for (int i = t; i < NB2; i += 256) cnt[i] = 0;
    __syncthreads();
    unsigned int code = pcode[p];
    bool kept = (code != 0xFFFFFFFFu);
    int bk = (int)(code >> 7);
    int lr = 0;
    if (kept) lr = atomicAdd(&cnt[bk], 1);
    __syncthreads();
    for (int i = t; i < NB2; i += 256) {
        int c = cnt[i];
        if (c) cnt[i] = atomicAdd(&cursor[i], c);   // overwrite with global base
    }
    __syncthreads();
    if (kept) {
        int r   = (int)(code & 127u);
        int bh  = bk >> 1;
        int g0  = bh % NX0;
        int g1  = (bk & 1) * 100 + r;
        entries[cnt[bk] + lr] = ((unsigned int)(g0 & 15) << 27) |
                                ((unsigned int)g1 << 19) | (unsigned int)p;
    }
}

// RENDER: grid = (batch, channel-quad cg, interleave-class k) = 3200 blocks x
// 256 threads, 12.8 KB LDS -> 8 blocks/CU resident, 12.5 blocks/CU total
// (scheduler refill absorbs residual density skew). Block k sweeps groups
// {k, k+25} (4 rows each). Each entry is decoded once per channel-QUAD
// (16 decode passes over entries instead of 32): float4 x_feats load,
// 4 LDS atomics. Then sole-writer dense float4 stores. No global atomics.
__global__ void __launch_bounds__(256) render_kernel(
        const float* __restrict__ x_feats,
        const unsigned int* __restrict__ entries,
        const int* __restrict__ offsets,
        float* __restrict__ out) {
    __shared__ float acc[NCH * RROWS * NX1];   // 12.8 KB: [ch][row][g1]
    const int CHS = RROWS * NX1;               // 800: channel stride in acc
    int blk = blockIdx.x;
    int k   = blk % KINT;
    int cg  = (blk / KINT) & 15;               // channel quad
    int b   = blk / (KINT * 16);               // batch
    int c0  = cg * NCH;
    int t   = threadIdx.x;

    for (int g = k; g < NGRP; g += KINT) {     // exactly 2 iterations
        int row0 = g * RROWS;

        // zero acc (all 4 channel slabs)
        for (int i = t; i < NCH * CHS; i += 256) acc[i] = 0.0f;
        __syncthreads();

        // accumulate entries of this group's buckets
        int bk0 = b * (NX0 * G1H) + row0 * G1H;
        int s = offsets[bk0];
        int e = offsets[bk0 + RROWS * G1H];
        for (int i = s + t; i < e; i += 256) {
            unsigned int v = entries[i];
            int p  = (int)(v & 0x7FFFFu);
            int g1 = (int)((v >> 19) & 0xFFu);
            int rl = (int)(v >> 27) & 3;       // row-local within 4-row group
            float4 f = *(const float4*)&x_feats[(size_t)p * C_ + c0];
            int a = rl * NX1 + g1;
            atomicAdd(&acc[a], f.x);
            atomicAdd(&acc[CHS + a], f.y);
            atomicAdd(&acc[2 * CHS + a], f.z);
            atomicAdd(&acc[3 * CHS + a], f.w);
        }
        __syncthreads();

        // sole-writer dense flush: 800 floats per channel, float4 stores
        size_t pl = ((size_t)b * C_ + c0) * (NX0 * NX1) + (size_t)row0 * NX1;
        const int nf4 = CHS / 4;               // 200 float4s per channel
        for (int k2 = t; k2 < NCH * nf4; k2 += 256) {
            int ch = k2 / nf4, kk = k2 - ch * nf4;
            float4 v4 = *(float4*)&acc[ch * CHS + kk * 4];
            *(float4*)&out[pl + (size_t)ch * (NX0 * NX1) + (size_t)kk * 4] = v4;
        }
        __syncthreads();   // protect acc before next group's zero
    }
}

extern "C" void kernel_launch(void* const* d_in, const int* in_sizes, int n_in,
                              void* d_out, int out_size, void* d_ws, size_t ws_size,
                              hipStream_t stream) {
    const float* x_feats    = (const float*)d_in[0];
    const float* rots       = (const float*)d_in[1];
    const float* trans      = (const float*)d_in[2];
    const float* intrins    = (const float*)d_in[3];
    const float* post_rots  = (const float*)d_in[4];
    const float* post_trans = (const float*)d_in[5];
    float* out = (float*)d_out;

    // ws layout (~2.8 MB)
    char* w = (char*)d_ws;
    float*        mats       = (float*)w;         w += 48 * 24 * sizeof(float);
    int*          counts     = (int*)w;           w += NB2 * sizeof(int);
    int*          offsets    = (int*)w;           w += (NB2 + 1) * sizeof(int);
    int*          cursor     = (int*)w;           w += NB2 * sizeof(int);
    unsigned int* pcode      = (unsigned int*)w;  w += NPRIME * sizeof(unsigned int);
    unsigned int* entries    = (unsigned int*)w;  w += NPRIME * sizeof(unsigned int);

    prep_kernel<<<1, 256, 0, stream>>>(rots, trans, intrins, post_rots, post_trans,
                                       mats, counts);
    geom_kernel<<<NBLK_PTS, 256, 0, stream>>>(mats, pcode, counts);
    scan_kernel<<<1, 128, 0, stream>>>(counts, offsets, cursor);
    place_kernel<<<NBLK_PTS, 256, 0, stream>>>(pcode, cursor, entries);
    render_kernel<<<B_ * 16 * KINT, 256, 0, stream>>>(x_feats, entries, offsets, out);
}

// Round 8
// 180.539 us; speedup vs baseline: 1.0870x; 1.0870x over previous
//
#include <hip/hip_runtime.h>

// LiftSplatShoot dims
#define B_   8
#define N_   6
#define D_   41
#define FH_  8
#define FW_  22
#define C_   64
#define NPRIME (B_*N_*D_*FH_*FW_)   // 346368 = 1353 * 256 exactly
#define NBLK_PTS 1353
#define PTS_PER_CAM (D_*FH_*FW_)    // 7216
#define NX0  200
#define NX1  200
#define G1H  2                      // g1 halves of 100
#define NB2  (B_ * NX0 * G1H)       // 3200 buckets (b, g0, g1/100)
#define OUTSZ (B_*C_*NX0*NX1)       // 20,480,000 floats
#define RROWS 4                     // g0 rows per render group
#define NGRP  50                    // 200/4 exactly -- no ragged tail
#define KINT  10                    // interleave: block k does g=k,k+10,..,k+40 (5 samples)
#define NCH   4                     // channels per render block (float4 x_feats load)

// ---------------- numpy-faithful fp32 3x3 inverse (LAPACK sgetrf+sgetri) ----
__device__ void lapack_inv3_f32(const float Ain[9], float Aout[9]) {
    #pragma clang fp contract(off)
    float a[9]; // column-major
    for (int r = 0; r < 3; ++r)
        for (int c = 0; c < 3; ++c)
            a[c*3 + r] = Ain[r*3 + c];
    int ipiv[3];
    for (int j = 0; j < 3; ++j) {
        int p = j;
        float amax = fabsf(a[j*3 + j]);
        for (int i = j + 1; i < 3; ++i) {
            float v = fabsf(a[j*3 + i]);
            if (v > amax) { amax = v; p = i; }
        }
        ipiv[j] = p;
        if (p != j)
            for (int c = 0; c < 3; ++c) { float t = a[c*3+j]; a[c*3+j] = a[c*3+p]; a[c*3+p] = t; }
        float d = 1.0f / a[j*3 + j];
        for (int i = j + 1; i < 3; ++i) a[j*3 + i] = a[j*3 + i] * d;
        for (int jj = j + 1; jj < 3; ++jj) {
            float temp = -a[jj*3 + j];
            for (int ii = j + 1; ii < 3; ++ii)
                a[jj*3 + ii] = a[jj*3 + ii] + a[j*3 + ii] * temp;
        }
    }
    for (int j = 0; j < 3; ++j) {
        float ajj_inv = 1.0f / a[j*3 + j];
        a[j*3 + j] = ajj_inv;
        float AJJ = -ajj_inv;
        for (int jj = 0; jj < j; ++jj) {
            float temp = a[j*3 + jj];
            for (int i = 0; i < jj; ++i)
                a[j*3 + i] = a[j*3 + i] + temp * a[jj*3 + i];
            a[j*3 + jj] = a[j*3 + jj] * a[jj*3 + jj];
        }
        for (int i = 0; i < j; ++i) a[j*3 + i] = a[j*3 + i] * AJJ;
    }
    float work[3];
    for (int j = 2; j >= 0; --j) {
        for (int i = j + 1; i < 3; ++i) { work[i] = a[j*3 + i]; a[j*3 + i] = 0.0f; }
        for (int jj = j + 1; jj < 3; ++jj) {
            float temp = -work[jj];
            for (int i = 0; i < 3; ++i)
                a[j*3 + i] = a[j*3 + i] + temp * a[jj*3 + i];
        }
    }
    for (int j = 2; j >= 0; --j) {
        int p = ipiv[j];
        if (p != j)
            for (int i = 0; i < 3; ++i) { float t = a[j*3+i]; a[j*3+i] = a[p*3+i]; a[p*3+i] = t; }
    }
    for (int r = 0; r < 3; ++r)
        for (int c = 0; c < 3; ++c)
            Aout[r*3 + c] = a[c*3 + r];
}

// prep (threads 0..47) + zero bucket counters.
__global__ void prep_kernel(const float* __restrict__ rots,
                            const float* __restrict__ trans,
                            const float* __restrict__ intrins,
                            const float* __restrict__ post_rots,
                            const float* __restrict__ post_trans,
                            float* __restrict__ mats,
                            int* __restrict__ counts) {
    #pragma clang fp contract(off)
    int t = threadIdx.x;
    for (int i = t; i < NB2; i += 256) counts[i] = 0;
    if (t >= B_ * N_) return;
    float pr[9], ipr[9], K[9], iK[9];
    for (int i = 0; i < 9; ++i) { pr[i] = post_rots[t*9 + i]; K[i] = intrins[t*9 + i]; }
    lapack_inv3_f32(pr, ipr);
    lapack_inv3_f32(K, iK);
    float* m = mats + t * 24;
    for (int i = 0; i < 9; ++i) m[i] = ipr[i];
    for (int i = 0; i < 3; ++i)
        for (int k = 0; k < 3; ++k) {
            float s = rots[t*9 + i*3 + 0] * iK[0*3 + k];
            s = s + rots[t*9 + i*3 + 1] * iK[1*3 + k];
            s = s + rots[t*9 + i*3 + 2] * iK[2*3 + k];
            m[9 + i*3 + k] = s;
        }
    for (int i = 0; i < 3; ++i) {
        m[18 + i] = post_trans[t*3 + i];
        m[21 + i] = trans[t*3 + i];
    }
}

// One thread per point (grid exact): fp32 numpy-faithful geometry ->
// pcode=(bk<<7)|r; block-local LDS histogram -> flush.
__global__ void __launch_bounds__(256) geom_kernel(
        const float* __restrict__ mats,
        unsigned int* __restrict__ pcode,
        int* __restrict__ counts) {
    #pragma clang fp contract(off)
    __shared__ unsigned int hist[NB2];   // 12.8 KB
    int t = threadIdx.x;
    int p = blockIdx.x * 256 + t;
    for (int i = t; i < NB2; i += 256) hist[i] = 0u;
    __syncthreads();

    int w  = p % FW_;
    int h  = (p / FW_) % FH_;
    int d  = (p / (FW_ * FH_)) % D_;
    int bn = p / PTS_PER_CAM;
    int b  = bn / N_;

    const float* m = mats + bn * 24;

    float xs = (w == FW_ - 1) ? 351.0f : (float)((double)w * (351.0 / 21.0));
    float ys = (h == FH_ - 1) ? 127.0f : (float)((double)h * (127.0 / 7.0));
    float ds = 4.0f + (float)d;

    float px = xs - m[18], py = ys - m[19], pz = ds - m[20];
    float qx = m[0]*px;  qx = qx + m[1]*py;  qx = qx + m[2]*pz;
    float qy = m[3]*px;  qy = qy + m[4]*py;  qy = qy + m[5]*pz;
    float qz = m[6]*px;  qz = qz + m[7]*py;  qz = qz + m[8]*pz;

    float ux = qx * qz, uy = qy * qz, uz = qz;

    float gx = m[9]*ux;   gx = gx + m[10]*uy;  gx = gx + m[11]*uz;  gx = gx + m[21];
    float gy = m[12]*ux;  gy = gy + m[13]*uy;  gy = gy + m[14]*uz;  gy = gy + m[22];
    float gz = m[15]*ux;  gz = gz + m[16]*uy;  gz = gz + m[17]*uz;  gz = gz + m[23];

    float cx = (gx - (-50.0f)) / 0.5f;
    float cy = (gy - (-50.0f)) / 0.5f;
    float cz = (gz - (-10.0f)) / 20.0f;
    int g0 = (int)cx;
    int g1 = (int)cy;
    int g2 = (int)cz;

    bool kept = (g0 >= 0) && (g0 < NX0) && (g1 >= 0) && (g1 < NX1) && (g2 == 0);
    if (kept) {
        int g1h = g1 / 100;
        int r   = g1 - g1h * 100;
        int bk  = (b * NX0 + g0) * G1H + g1h;
        pcode[p] = ((unsigned int)bk << 7) | (unsigned int)r;
        atomicAdd(&hist[bk], 1u);
    } else {
        pcode[p] = 0xFFFFFFFFu;
    }
    __syncthreads();
    for (int i = t; i < NB2; i += 256) {
        unsigned int hv = hist[i];
        if (hv) atomicAdd(&counts[i], (int)hv);
    }
}

// Single-block (128 threads): pure exclusive scan over 3200 counts ->
// offsets (+total at [NB2]) and cursor.
__global__ void scan_kernel(const int* __restrict__ counts,
                            int* __restrict__ offsets,
                            int* __restrict__ cursor) {
    __shared__ int ts[128];
    int t = threadIdx.x;
    const int PER = NB2 / 128; // 25
    int base = t * PER;
    int mysum = 0;
    for (int j = 0; j < PER; ++j) mysum += counts[base + j];
    ts[t] = mysum;
    __syncthreads();
    for (int off = 1; off < 128; off <<= 1) {
        int v = (t >= off) ? ts[t - off] : 0;
        __syncthreads();
        ts[t] += v;
        __syncthreads();
    }
    int run = (t > 0) ? ts[t - 1] : 0;
    for (int j = 0; j < PER; ++j) {
        offsets[base + j] = run;
        cursor[base + j]  = run;
        run += counts[base + j];
    }
    if (t == 127) offsets[NB2] = run;
}

// Compact kept points (block-aggregated reservation). Entry encodes
// (g0&15)<<27 | g1<<19 | p. Render groups have bases that are multiples
// of 4, so row-local = (g0&15)&3.
__global__ void __launch_bounds__(256) place_kernel(
        const unsigned int* __restrict__ pcode,
        int* __restrict__ cursor,
        unsigned int* __restrict__ entries) {
    __shared__ int cnt[NB2];   // 12.8 KB (counts, then global bases)
    int t = threadIdx.x;
    int p = blockIdx.x * 256 + t;
    for (int i = t; i < NB2; i += 256) cnt[i] = 0;
    __syncthreads();
    unsigned int code = pcode[p];
    bool kept = (code != 0xFFFFFFFFu);
    int bk = (int)(code >> 7);
    int lr = 0;
    if (kept) lr = atomicAdd(&cnt[bk], 1);
    __syncthreads();
    for (int i = t; i < NB2; i += 256) {
        int c = cnt[i];
        if (c) cnt[i] = atomicAdd(&cursor[i], c);   // overwrite with global base
    }
    __syncthreads();
    if (kept) {
        int r   = (int)(code & 127u);
        int bh  = bk >> 1;
        int g0  = bh % NX0;
        int g1  = (bk & 1) * 100 + r;
        entries[cnt[bk] + lr] = ((unsigned int)(g0 & 15) << 27) |
                                ((unsigned int)g1 << 19) | (unsigned int)p;
    }
}

// RENDER: grid = (batch, channel-quad cg, interleave-class k) = 1280 blocks x
// 256 threads, 12.8 KB LDS. Block k sweeps groups {k, k+10, ..., k+40}
// (5 windows of 4 rows at stride 40 -- the 5-sample interleave that balanced
// round 6, now with 16 decode passes over entries instead of 32). Each tile:
// LDS-accumulate (float4 x_feats load, 4 LDS atomics), then sole-writer
// dense float4 stores. No global atomics.
__global__ void __launch_bounds__(256) render_kernel(
        const float* __restrict__ x_feats,
        const unsigned int* __restrict__ entries,
        const int* __restrict__ offsets,
        float* __restrict__ out) {
    __shared__ float acc[NCH * RROWS * NX1];   // 12.8 KB: [ch][row][g1]
    const int CHS = RROWS * NX1;               // 800: channel stride in acc
    int blk = blockIdx.x;
    int k   = blk % KINT;
    int cg  = (blk / KINT) & 15;               // channel quad
    int b   = blk / (KINT * 16);               // batch
    int c0  = cg * NCH;
    int t   = threadIdx.x;

    for (int g = k; g < NGRP; g += KINT) {     // exactly 5 iterations
        int row0 = g * RROWS;

        // zero acc (all 4 channel slabs)
        for (int i = t; i < NCH * CHS; i += 256) acc[i] = 0.0f;
        __syncthreads();

        // accumulate entries of this group's buckets
        int bk0 = b * (NX0 * G1H) + row0 * G1H;
        int s = offsets[bk0];
        int e = offsets[bk0 + RROWS * G1H];
        for (int i = s + t; i < e; i += 256) {
            unsigned int v = entries[i];
            int p  = (int)(v & 0x7FFFFu);
            int g1 = (int)((v >> 19) & 0xFFu);
            int rl = (int)(v >> 27) & 3;       // row-local within 4-row group
            float4 f = *(const float4*)&x_feats[(size_t)p * C_ + c0];
            int a = rl * NX1 + g1;
            atomicAdd(&acc[a], f.x);
            atomicAdd(&acc[CHS + a], f.y);
            atomicAdd(&acc[2 * CHS + a], f.z);
            atomicAdd(&acc[3 * CHS + a], f.w);
        }
        __syncthreads();

        // sole-writer dense flush: 800 floats per channel, float4 stores
        size_t pl = ((size_t)b * C_ + c0) * (NX0 * NX1) + (size_t)row0 * NX1;
        const int nf4 = CHS / 4;               // 200 float4s per channel
        #pragma unroll
        for (int ch = 0; ch < NCH; ++ch) {
            for (int kk = t; kk < nf4; kk += 256) {
                float4 v4 = *(float4*)&acc[ch * CHS + kk * 4];
                *(float4*)&out[pl + (size_t)ch * (NX0 * NX1) + (size_t)kk * 4] = v4;
            }
        }
        __syncthreads();   // protect acc before next group's zero
    }
}

extern "C" void kernel_launch(void* const* d_in, const int* in_sizes, int n_in,
                              void* d_out, int out_size, void* d_ws, size_t ws_size,
                              hipStream_t stream) {
    const float* x_feats    = (const float*)d_in[0];
    const float* rots       = (const float*)d_in[1];
    const float* trans      = (const float*)d_in[2];
    const float* intrins    = (const float*)d_in[3];
    const float* post_rots  = (const float*)d_in[4];
    const float* post_trans = (const float*)d_in[5];
    float* out = (float*)d_out;

    // ws layout (~2.8 MB)
    char* w = (char*)d_ws;
    float*        mats       = (float*)w;         w += 48 * 24 * sizeof(float);
    int*          counts     = (int*)w;           w += NB2 * sizeof(int);
    int*          offsets    = (int*)w;           w += (NB2 + 1) * sizeof(int);
    int*          cursor     = (int*)w;           w += NB2 * sizeof(int);
    unsigned int* pcode      = (unsigned int*)w;  w += NPRIME * sizeof(unsigned int);
    unsigned int* entries    = (unsigned int*)w;  w += NPRIME * sizeof(unsigned int);

    prep_kernel<<<1, 256, 0, stream>>>(rots, trans, intrins, post_rots, post_trans,
                                       mats, counts);
    geom_kernel<<<NBLK_PTS, 256, 0, stream>>>(mats, pcode, counts);
    scan_kernel<<<1, 128, 0, stream>>>(counts, offsets, cursor);
    place_kernel<<<NBLK_PTS, 256, 0, stream>>>(pcode, cursor, entries);
    render_kernel<<<B_ * 16 * KINT, 256, 0, stream>>>(x_feats, entries, offsets, out);
}